// Round 9
// baseline (315.606 us; speedup 1.0000x reference)
//
#include <hip/hip_runtime.h>
#include <hip/hip_bf16.h>

// B=2, T=2048, C=1024, H=16, HD=64. f32 I/O; bf16 MFMA internally, f32 accum.
//
//   0) prep (fused): x -> xb bf16; w_qkv,w_out -> bf16 W^T[N][K]
//   1) gemm_glds<EPI=1,BN=128>: qkv proj. Q pre-scaled -> qk; K -> qk;
//      V -> vt[B,H,64,T].
//   2) repack: K,V -> FRAGMENT-MAJOR buffers kfb,vfb (per bh,chunk: the
//      exact 8-short groups each attn lane loads, lane-contiguous).
//      Round-8 lesson: direct-global K/V frag loads are 16-line scattered
//      (lanes' c16 rows 4KB apart) -> ~50K L1 transactions/CU -> 114us
//      latency-bound. Fragment-major makes every attn load a coalesced
//      1KB b128. Repack moves 32MB (L2/L3-resident), ~8-10us.
//   3) attn_mfma: flash attention, static exp2 softmax, 2x2 wave split
//      (round-7 verified): wave w = q-half wq=w&1 x key-half ws=w>>1; P
//      feeds PV A-frag directly from registers; l via ones-MFMA (round-8
//      verified). ZERO-LDS main loop, no barriers; K = 4 coalesced b128,
//      V = 4 coalesced b128 per chunk. Pair merge through 20KB LDS (one
//      barrier). All O/O1 indices compile-time (rule #20). VGPR ~60 ->
//      launch_bounds(256,6) = 6 blocks/CU = 24 waves/CU.
//   4) gemm_glds<EPI=0,BN=64>: out proj -> d_out f32

#define B_ 2
#define T_ 2048
#define C_ 1024
#define H_ 16
#define HD_ 64
#define M_ (B_ * T_)      // 4096
#define N3_ (3 * C_)      // 3072
#define QK2_ 2048
#define QSCALE 0.18033688f   // 0.125 * log2(e)

typedef __attribute__((ext_vector_type(8))) short short8;
typedef __attribute__((ext_vector_type(4))) short short4v;
typedef __attribute__((ext_vector_type(4))) float floatx4;

__device__ __forceinline__ unsigned short f2b(float f) {
    __hip_bfloat16 h = __float2bfloat16(f);
    return *reinterpret_cast<unsigned short*>(&h);
}

__device__ __forceinline__ float fexp2(float x) {
#if __has_builtin(__builtin_amdgcn_exp2f)
    return __builtin_amdgcn_exp2f(x);
#else
    return exp2f(x);
#endif
}

__device__ __forceinline__ void glds16(const void* g, void* l) {
    __builtin_amdgcn_global_load_lds(
        (const __attribute__((address_space(1))) void*)g,
        (__attribute__((address_space(3))) void*)l, 16, 0, 0);
}

// ---------------------------------------------------------------------------
// Fused prep. seg0 (4096 blocks): x f32->bf16. seg1 (1536): w_qkv -> wt1
// [3072][1024] via 64(k)x32(n) tiles, short8 coalesced writes. seg2 (512):
// w_out -> wt2.
// ---------------------------------------------------------------------------
__global__ __launch_bounds__(256) void prep(
    const float* __restrict__ x, const float* __restrict__ w_qkv,
    const float* __restrict__ w_out, unsigned short* __restrict__ xb,
    unsigned short* __restrict__ wt1, unsigned short* __restrict__ wt2) {
    __shared__ float t[64][33];
    const int bi = blockIdx.x;
    const int tid = threadIdx.x;
    if (bi < 4096) {
        int i = (bi * 256 + tid) * 4;
        float4 v = *reinterpret_cast<const float4*>(x + i);
        short4v s;
        s[0] = (short)f2b(v.x); s[1] = (short)f2b(v.y);
        s[2] = (short)f2b(v.z); s[3] = (short)f2b(v.w);
        *reinterpret_cast<short4v*>(xb + i) = s;
        return;
    }
    const float* src; unsigned short* dst; int n0, k0, N;
    if (bi < 4096 + 1536) {
        int u = bi - 4096;
        src = w_qkv; dst = wt1; N = N3_;
        k0 = (u & 15) * 64; n0 = (u >> 4) * 32;
    } else {
        int u = bi - (4096 + 1536);
        src = w_out; dst = wt2; N = C_;
        k0 = (u & 15) * 64; n0 = (u >> 4) * 32;
    }
    const int tx = tid & 31, ty = tid >> 5;
#pragma unroll
    for (int i = 0; i < 8; i++)
        t[ty + i * 8][tx] = src[(size_t)(k0 + ty + i * 8) * N + n0 + tx];
    __syncthreads();
    const int row = tid >> 3;
    const int kp  = (tid & 7) * 8;
    short8 o;
#pragma unroll
    for (int j = 0; j < 8; j++) o[j] = (short)f2b(t[kp + j][row]);
    *reinterpret_cast<short8*>(&dst[(size_t)(n0 + row) * C_ + k0 + kp]) = o;
}

// ---------------------------------------------------------------------------
// GEMM: C[M,N] = A[M,K] @ Bt^T[N,K] + bias[N]. A,Bt bf16. Tile 128 x BN,
// BK=64, 4 waves 2x2. LDS rows 64 shorts, XOR chunk swizzle; glds16 staging.
// 1D grid, XCD-banded (neutral-at-worst heuristic).
// ---------------------------------------------------------------------------
template<int EPI, int BN>
__global__ __launch_bounds__(256) void gemm_glds(
    const unsigned short* __restrict__ A, const unsigned short* __restrict__ Bt,
    const float* __restrict__ bias, void* __restrict__ Cp,
    unsigned short* __restrict__ vtp, int M, int N, int K) {
    constexpr int NI = BN / 32;
    __shared__ __align__(16) unsigned short Al[128 * 64];
    __shared__ __align__(16) unsigned short Bl[BN * 64];

    const int tid  = threadIdx.x;
    const int lane = tid & 63;
    const int w    = tid >> 6;
    const int c16  = lane & 15;
    const int quad = lane >> 4;
    const int NT  = N / BN;
    const int pe  = NT >> 3;
    const int xcd = blockIdx.x & 7;
    const int ii  = blockIdx.x >> 3;
    const int n0  = (xcd * pe + ii % pe) * BN;
    const int m0  = (ii / pe) * 128;
    const int wm = (w >> 1) * 64;
    const int wn = (w & 1) * (BN / 2);

    floatx4 acc[4][NI] = {};

    const int srow = lane >> 3;
    const int sch  = ((lane & 7) ^ srow) * 8;
    const unsigned short* ag = A + (size_t)(m0 + w * 32 + srow) * K + sch;
    const unsigned short* bg = Bt + (size_t)(n0 + w * (BN / 4) + srow) * K + sch;

    const int s7 = c16 & 7;

    for (int k0 = 0; k0 < K; k0 += 64) {
        __syncthreads();
#pragma unroll
        for (int i = 0; i < 4; i++)
            glds16(ag + k0 + (size_t)(i * 8) * K, &Al[(w * 32 + i * 8) * 64]);
#pragma unroll
        for (int i = 0; i < BN / 32; i++)
            glds16(bg + k0 + (size_t)(i * 8) * K,
                   &Bl[(w * (BN / 4) + i * 8) * 64]);
        __syncthreads();

        short8 af[4][2], bf[NI][2];
#pragma unroll
        for (int im = 0; im < 4; im++)
#pragma unroll
            for (int kk = 0; kk < 2; kk++)
                af[im][kk] = *reinterpret_cast<const short8*>(
                    &Al[(wm + im * 16 + c16) * 64 + ((kk * 4 + quad) ^ s7) * 8]);
#pragma unroll
        for (int in = 0; in < NI; in++)
#pragma unroll
            for (int kk = 0; kk < 2; kk++)
                bf[in][kk] = *reinterpret_cast<const short8*>(
                    &Bl[(wn + in * 16 + c16) * 64 + ((kk * 4 + quad) ^ s7) * 8]);
#pragma unroll
        for (int im = 0; im < 4; im++)
#pragma unroll
            for (int in = 0; in < NI; in++)
#pragma unroll
                for (int kk = 0; kk < 2; kk++)
                    acc[im][in] = __builtin_amdgcn_mfma_f32_16x16x32_bf16(
                        af[im][kk], bf[in][kk], acc[im][in], 0, 0, 0);
    }

    const int ncol = n0 + wn;
    float bv[NI];
#pragma unroll
    for (int in = 0; in < NI; in++) bv[in] = bias[ncol + in * 16 + c16];

    if (EPI == 0) {
        float* C = (float*)Cp;
#pragma unroll
        for (int im = 0; im < 4; im++)
#pragma unroll
            for (int r = 0; r < 4; r++) {
                int row = m0 + wm + im * 16 + quad * 4 + r;
#pragma unroll
                for (int in = 0; in < NI; in++)
                    C[(size_t)row * N + ncol + in * 16 + c16] =
                        acc[im][in][r] + bv[in];
            }
    } else {
        if (ncol < 2 * C_) {
            const float fac = (ncol < C_) ? QSCALE : 1.0f;
            unsigned short* qkp = (unsigned short*)Cp;
#pragma unroll
            for (int im = 0; im < 4; im++)
#pragma unroll
                for (int r = 0; r < 4; r++) {
                    int row = m0 + wm + im * 16 + quad * 4 + r;
#pragma unroll
                    for (int in = 0; in < NI; in++)
                        qkp[(size_t)row * QK2_ + ncol + in * 16 + c16] =
                            f2b((acc[im][in][r] + bv[in]) * fac);
                }
        } else {                 // V -> vt[B,H,64,T]
#pragma unroll
            for (int im = 0; im < 4; im++) {
                int row0 = m0 + wm + im * 16 + quad * 4;
                int b  = row0 >> 11;
                int t0 = row0 & (T_ - 1);
#pragma unroll
                for (int in = 0; in < NI; in++) {
                    int dfull = ncol - 2 * C_ + in * 16 + c16;
                    short4v sv;
#pragma unroll
                    for (int r = 0; r < 4; r++)
                        sv[r] = (short)f2b(acc[im][in][r] + bv[in]);
                    *reinterpret_cast<short4v*>(
                        &vtp[(((size_t)(b << 10) + dfull) << 11) + t0]) = sv;
                }
            }
        }
    }
}

// ---------------------------------------------------------------------------
// Repack K,V into fragment-major buffers. 1024 blocks = (bh 32) x (chunk 32),
// 256 thr. Per (bh,chunk) region = 4096 shorts (8KB) each for K and V.
//   K frag f = ws*4+sub*2+dhalf, lane ll=quad*16+c16, j=0..7:
//     K[key=chunk*64+ws*32+sub*16+c16][d=dhalf*32+quad*8+j]
//   V frag f = ws*4+dt, lane ll, j:
//     V[d=dt*16+c16][key=chunk*64+ws*32 + (j<4 ? quad*4+j : 16+quad*4+j-4)]
// Thread tid handles frag=tid>>5, lanes ll=(tid&31)*2, +1. Writes coalesced
// short8; reads 16B/8B granules (L2/L3-resident).
// ---------------------------------------------------------------------------
__global__ __launch_bounds__(256) void repack(
    const unsigned short* __restrict__ qk, const unsigned short* __restrict__ vt,
    unsigned short* __restrict__ kfb, unsigned short* __restrict__ vfb) {
    const int bh    = blockIdx.x >> 5;
    const int chunk = blockIdx.x & 31;
    const int b = bh >> 4, h = bh & 15;
    const int tid  = threadIdx.x;
    const int frag = tid >> 5;
    const int ll0  = (tid & 31) * 2;
    const size_t obase = ((size_t)(bh * 32 + chunk)) * 4096 + frag * 512;

    {   // K: frag = ws*4 + sub*2 + dhalf
        const int ws = frag >> 2, sub = (frag >> 1) & 1, dh = frag & 1;
#pragma unroll
        for (int e = 0; e < 2; e++) {
            const int ll = ll0 + e, quad = ll >> 4, c16 = ll & 15;
            const int key = chunk * 64 + ws * 32 + sub * 16 + c16;
            short8 v = *reinterpret_cast<const short8*>(
                qk + ((size_t)(b * T_ + key)) * QK2_ + C_ + h * HD_ +
                dh * 32 + quad * 8);
            *reinterpret_cast<short8*>(kfb + obase + ll * 8) = v;
        }
    }
    {   // V: frag = ws*4 + dt
        const int ws = frag >> 2, dt = frag & 3;
#pragma unroll
        for (int e = 0; e < 2; e++) {
            const int ll = ll0 + e, quad = ll >> 4, c16 = ll & 15;
            const int d = dt * 16 + c16;
            const unsigned short* src = vt + ((size_t)(bh * 64 + d)) * T_ +
                                        chunk * 64 + ws * 32 + quad * 4;
            short4v v0 = *reinterpret_cast<const short4v*>(src);
            short4v v1 = *reinterpret_cast<const short4v*>(src + 16);
            short8 o;
            o[0] = v0[0]; o[1] = v0[1]; o[2] = v0[2]; o[3] = v0[3];
            o[4] = v1[0]; o[5] = v1[1]; o[6] = v1[2]; o[7] = v1[3];
            *reinterpret_cast<short8*>(vfb + obase + ll * 8) = o;
        }
    }
}

// ---------------------------------------------------------------------------
// One 64-key chunk, one wave: key-half ws x this wave's 32 q rows.
// Fragment-major operands: 4 K b128 + 4 V b128, all COALESCED (lane*16B
// contiguous). Same math as round-8 (verified): S^T per 16-key sub; PV
// window {sub0:quad*4+r, sub1:+16}; l via ones-MFMA.
// ---------------------------------------------------------------------------
#define ATTN_CHUNK(MASKED, kb, kcp, vcp)                                      \
{                                                                             \
    short8 kf00 = *reinterpret_cast<const short8*>((kcp));                    \
    short8 kf01 = *reinterpret_cast<const short8*>((kcp) + 512);              \
    short8 kf10 = *reinterpret_cast<const short8*>((kcp) + 1024);             \
    short8 kf11 = *reinterpret_cast<const short8*>((kcp) + 1536);             \
    short8 vf[4];                                                             \
    _Pragma("unroll")                                                         \
    for (int dt = 0; dt < 4; dt++)                                            \
        vf[dt] = *reinterpret_cast<const short8*>((vcp) + dt * 512);          \
    short8 pf[2];                                                             \
    _Pragma("unroll")                                                         \
    for (int qt = 0; qt < 2; qt++) {                                          \
        floatx4 s0 = __builtin_amdgcn_mfma_f32_16x16x32_bf16(                 \
            kf00, af[qt][0], z, 0, 0, 0);                                     \
        s0 = __builtin_amdgcn_mfma_f32_16x16x32_bf16(                         \
            kf01, af[qt][1], s0, 0, 0, 0);                                    \
        floatx4 s1 = __builtin_amdgcn_mfma_f32_16x16x32_bf16(                 \
            kf10, af[qt][0], z, 0, 0, 0);                                     \
        s1 = __builtin_amdgcn_mfma_f32_16x16x32_bf16(                         \
            kf11, af[qt][1], s1, 0, 0, 0);                                    \
        short8 p8;                                                            \
        _Pragma("unroll")                                                     \
        for (int r = 0; r < 4; r++) {                                         \
            float p0, p1;                                                     \
            if (MASKED) {                                                     \
                int key0 = (kb) + ws * 32 + quad * 4 + r;                     \
                int qr = q0 + wq * 32 + qt * 16 + c16;                        \
                p0 = (key0 <= qr) ? fexp2(s0[r]) : 0.f;                       \
                p1 = (key0 + 16 <= qr) ? fexp2(s1[r]) : 0.f;                  \
            } else {                                                          \
                p0 = fexp2(s0[r]);                                            \
                p1 = fexp2(s1[r]);                                            \
            }                                                                 \
            p8[r] = (short)f2b(p0);                                           \
            p8[4 + r] = (short)f2b(p1);                                       \
        }                                                                     \
        pf[qt] = p8;                                                          \
    }                                                                         \
    _Pragma("unroll")                                                         \
    for (int qt = 0; qt < 2; qt++)                                            \
        O1[qt] = __builtin_amdgcn_mfma_f32_16x16x32_bf16(                     \
            pf[qt], ones, O1[qt], 0, 0, 0);                                   \
    _Pragma("unroll")                                                         \
    for (int dt = 0; dt < 4; dt++)                                            \
        _Pragma("unroll")                                                     \
        for (int qt = 0; qt < 2; qt++)                                        \
            O[qt][dt] = __builtin_amdgcn_mfma_f32_16x16x32_bf16(              \
                pf[qt], vf[dt], O[qt][dt], 0, 0, 0);                          \
}

// ---------------------------------------------------------------------------
// Flash attention, 2x2 wave split, zero-LDS main loop, fragment-major K/V.
// Block = 256 thr = 4 waves; block t owns Q rows [64t,64t+64), nch=t+1,
// LPT. Wave w: q-half wq=w&1 (Q in regs), key-half ws=w>>1. No barriers in
// the loop. Pair merge through 20KB LDS (one barrier). All O/O1 indices
// compile-time (rule #20). Fully-masked {wq0,ws1} diagonal corner skipped.
// launch_bounds(256,6): VGPR cap ~85 (round-8 body used 60) -> 6 blocks/CU.
// ---------------------------------------------------------------------------
__global__ __launch_bounds__(256, 6) void attn_mfma(
    const unsigned short* __restrict__ qk,
    const unsigned short* __restrict__ kfb,
    const unsigned short* __restrict__ vfb,
    unsigned short* __restrict__ y) {
    __shared__ __align__(16) float Of[4096];   // [wq][qt][dt][lane][4]
    __shared__ __align__(16) float Lb[1024];   // [wq][qt][lane][4] (O1 park)

    const int tid  = threadIdx.x;
    const int lane = tid & 63;
    const int w    = tid >> 6;          // 0..3
    const int wq   = w & 1;             // q-half
    const int ws   = w >> 1;            // key-half
    const int c16  = lane & 15;
    const int quad = lane >> 4;
    const int bh = blockIdx.x & 31;
    const int t  = 31 - (blockIdx.x >> 5);   // longest-first
    const int b  = bh >> 4;
    const int h  = bh & 15;
    const int q0 = t * 64;
    const int nch = t + 1;

    const unsigned short* qrow = qk + (size_t)b * T_ * QK2_ + h * HD_;
    const unsigned short* kfp = kfb + ((size_t)bh * 32) * 4096 + ws * 2048 + lane * 8;
    const unsigned short* vfp = vfb + ((size_t)bh * 32) * 4096 + ws * 2048 + lane * 8;

    // Q in registers: af[qt][hh] = Q[q0+wq*32+qt*16+c16][hh*32+quad*8 ..+8]
    short8 af[2][2];
#pragma unroll
    for (int qt = 0; qt < 2; qt++)
#pragma unroll
        for (int hh = 0; hh < 2; hh++)
            af[qt][hh] = *reinterpret_cast<const short8*>(
                qrow + (size_t)(q0 + wq * 32 + qt * 16 + c16) * QK2_ +
                hh * 32 + quad * 8);

    floatx4 O[2][4] = {};
    floatx4 O1[2] = {};                  // row-sums l via ones-MFMA
    const floatx4 z = {0.f, 0.f, 0.f, 0.f};
    short8 ones;
#pragma unroll
    for (int j = 0; j < 8; j++) ones[j] = (short)0x3F80;   // bf16 1.0

    for (int c = 0; c < nch; c++) {
        const int kb = c * 64;
        const unsigned short* kcp = kfp + (size_t)c * 4096;
        const unsigned short* vcp = vfp + (size_t)c * 4096;
        if (c + 1 < nch) {
            ATTN_CHUNK(0, kb, kcp, vcp)
        } else if (!(wq == 0 && ws == 1)) {
            // diagonal chunk; {wq0,ws1} corner is fully masked -> skip
            ATTN_CHUNK(1, kb, kcp, vcp)
        }
    }

    // ---- pair merge: O_total = O(ws=0) + O(ws=1) per q-half.
    // ws=1 parks O (32 f32/lane) + O1 in LDS; ws=0 partners add and write.
    if (ws) {
#pragma unroll
        for (int qt = 0; qt < 2; qt++) {
#pragma unroll
            for (int dt = 0; dt < 4; dt++)
                *reinterpret_cast<floatx4*>(
                    &Of[wq * 2048 + qt * 1024 + dt * 256 + lane * 4]) = O[qt][dt];
            *reinterpret_cast<floatx4*>(
                &Lb[wq * 512 + qt * 256 + lane * 4]) = O1[qt];
        }
    }
    __syncthreads();
    if (ws == 0) {
#pragma unroll
        for (int qt = 0; qt < 2; qt++) {
#pragma unroll
            for (int dt = 0; dt < 4; dt++)
                O[qt][dt] += *reinterpret_cast<const floatx4*>(
                    &Of[wq * 2048 + qt * 1024 + dt * 256 + lane * 4]);
            floatx4 lr = O1[qt] + *reinterpret_cast<const floatx4*>(
                    &Lb[wq * 512 + qt * 256 + lane * 4]);

            // write rows q0+wq*32+qt*16+quad*4+r, cols h*HD+dt*16+c16
#pragma unroll
            for (int dt = 0; dt < 4; dt++)
#pragma unroll
                for (int r = 0; r < 4; r++) {
                    float val = O[qt][dt][r] / fmaxf(lr[r], 1e-30f);
                    y[((size_t)b * T_ + q0 + wq * 32 + qt * 16 + quad * 4 + r)
                          * C_ + h * HD_ + dt * 16 + c16] = f2b(val);
                }
        }
    }
}

extern "C" void kernel_launch(void* const* d_in, const int* in_sizes, int n_in,
                              void* d_out, int out_size, void* d_ws, size_t ws_size,
                              hipStream_t stream) {
    const float* x     = (const float*)d_in[0];
    const float* w_qkv = (const float*)d_in[1];
    const float* b_qkv = (const float*)d_in[2];
    const float* w_out = (const float*)d_in[3];
    const float* b_out = (const float*)d_in[4];
    float* out = (float*)d_out;

    unsigned short* qkb = (unsigned short*)d_ws;                 // [4096][2048]
    unsigned short* vtb = qkb + (size_t)M_ * QK2_;               // [B,H,64,T]
    unsigned short* yb  = vtb + (size_t)B_ * H_ * HD_ * T_;      // [4096][1024]
    unsigned short* wt1 = yb + (size_t)M_ * C_;                  // [3072][1024]
    unsigned short* wt2 = wt1 + (size_t)N3_ * C_;                // [1024][1024]
    unsigned short* xb  = wt2 + (size_t)C_ * C_;                 // [4096][1024]
    unsigned short* kfb = xb + (size_t)M_ * C_;                  // [32*32][4096]
    unsigned short* vfb = kfb + (size_t)32 * 32 * 4096;          // [32*32][4096]

    prep<<<4096 + 1536 + 512, 256, 0, stream>>>(x, w_qkv, w_out, xb, wt1, wt2);

    gemm_glds<1, 128><<<(N3_ / 128) * (M_ / 128), 256, 0, stream>>>(
        xb, wt1, b_qkv, qkb, vtb, M_, N3_, C_);

    repack<<<32 * 32, 256, 0, stream>>>(qkb, vtb, kfb, vfb);

    attn_mfma<<<B_ * H_ * 32, 256, 0, stream>>>(qkb, kfb, vfb, yb);

    gemm_glds<0, 64><<<(C_ / 64) * (M_ / 128), 256, 0, stream>>>(
        yb, wt2, b_out, out, nullptr, M_, C_, C_);
}

// Round 10
// 179.855 us; speedup vs baseline: 1.7548x; 1.7548x over previous
//
#include <hip/hip_runtime.h>
#include <hip/hip_bf16.h>

// B=2, T=2048, C=1024, H=16, HD=64. f32 I/O; bf16 MFMA internally, f32 accum.
//
//   0) prep (fused): x -> xb bf16; w_qkv,w_out -> bf16 W^T[N][K]
//   1) gemm_glds<EPI=1,BN=128>: qkv proj. Q pre-scaled -> qk; K -> qk;
//      V -> vt[B,H,64,T].
//   2) repack: K,V -> FRAGMENT-MAJOR buffers kfb,vfb (per bh,chunk: the
//      exact 8-short groups each attn lane loads, lane-contiguous).
//      Round-8 lesson: direct-global K/V frag loads are 16-line scattered
//      -> latency-bound. Fragment-major makes every attn load a coalesced
//      1KB b128. Repack moves 32MB (L2/L3-resident), ~10us.
//   3) attn_mfma: flash attention, static exp2 softmax, 2x2 wave split
//      (round-7 verified): wave w = q-half wq=w&1 x key-half ws=w>>1; P
//      feeds PV A-frag directly from registers; l via ones-MFMA (round-8
//      verified). ZERO-LDS main loop, no barriers; K = 4 coalesced b128,
//      V = 4 coalesced b128 per chunk. Pair merge through 20KB LDS (one
//      barrier). All O/O1 indices compile-time (rule #20).
//      ROUND-10 FIX: round-9 set launch_bounds(256,6) -> VGPR cap 84 <
//      body demand (~100-120 scheduled) -> 314MB scratch spill. Restore
//      launch_bounds(256,3) (cap ~170; round-8-verified spill-free,
//      natural usage ~60 -> runtime occupancy up to 8 blocks/CU anyway).
//   4) gemm_glds<EPI=0,BN=64>: out proj -> d_out f32

#define B_ 2
#define T_ 2048
#define C_ 1024
#define H_ 16
#define HD_ 64
#define M_ (B_ * T_)      // 4096
#define N3_ (3 * C_)      // 3072
#define QK2_ 2048
#define QSCALE 0.18033688f   // 0.125 * log2(e)

typedef __attribute__((ext_vector_type(8))) short short8;
typedef __attribute__((ext_vector_type(4))) short short4v;
typedef __attribute__((ext_vector_type(4))) float floatx4;

__device__ __forceinline__ unsigned short f2b(float f) {
    __hip_bfloat16 h = __float2bfloat16(f);
    return *reinterpret_cast<unsigned short*>(&h);
}

__device__ __forceinline__ float fexp2(float x) {
#if __has_builtin(__builtin_amdgcn_exp2f)
    return __builtin_amdgcn_exp2f(x);
#else
    return exp2f(x);
#endif
}

__device__ __forceinline__ void glds16(const void* g, void* l) {
    __builtin_amdgcn_global_load_lds(
        (const __attribute__((address_space(1))) void*)g,
        (__attribute__((address_space(3))) void*)l, 16, 0, 0);
}

// ---------------------------------------------------------------------------
// Fused prep. seg0 (4096 blocks): x f32->bf16. seg1 (1536): w_qkv -> wt1
// [3072][1024] via 64(k)x32(n) tiles, short8 coalesced writes. seg2 (512):
// w_out -> wt2.
// ---------------------------------------------------------------------------
__global__ __launch_bounds__(256) void prep(
    const float* __restrict__ x, const float* __restrict__ w_qkv,
    const float* __restrict__ w_out, unsigned short* __restrict__ xb,
    unsigned short* __restrict__ wt1, unsigned short* __restrict__ wt2) {
    __shared__ float t[64][33];
    const int bi = blockIdx.x;
    const int tid = threadIdx.x;
    if (bi < 4096) {
        int i = (bi * 256 + tid) * 4;
        float4 v = *reinterpret_cast<const float4*>(x + i);
        short4v s;
        s[0] = (short)f2b(v.x); s[1] = (short)f2b(v.y);
        s[2] = (short)f2b(v.z); s[3] = (short)f2b(v.w);
        *reinterpret_cast<short4v*>(xb + i) = s;
        return;
    }
    const float* src; unsigned short* dst; int n0, k0, N;
    if (bi < 4096 + 1536) {
        int u = bi - 4096;
        src = w_qkv; dst = wt1; N = N3_;
        k0 = (u & 15) * 64; n0 = (u >> 4) * 32;
    } else {
        int u = bi - (4096 + 1536);
        src = w_out; dst = wt2; N = C_;
        k0 = (u & 15) * 64; n0 = (u >> 4) * 32;
    }
    const int tx = tid & 31, ty = tid >> 5;
#pragma unroll
    for (int i = 0; i < 8; i++)
        t[ty + i * 8][tx] = src[(size_t)(k0 + ty + i * 8) * N + n0 + tx];
    __syncthreads();
    const int row = tid >> 3;
    const int kp  = (tid & 7) * 8;
    short8 o;
#pragma unroll
    for (int j = 0; j < 8; j++) o[j] = (short)f2b(t[kp + j][row]);
    *reinterpret_cast<short8*>(&dst[(size_t)(n0 + row) * C_ + k0 + kp]) = o;
}

// ---------------------------------------------------------------------------
// GEMM: C[M,N] = A[M,K] @ Bt^T[N,K] + bias[N]. A,Bt bf16. Tile 128 x BN,
// BK=64, 4 waves 2x2. LDS rows 64 shorts, XOR chunk swizzle; glds16 staging.
// 1D grid, XCD-banded (neutral-at-worst heuristic).
// ---------------------------------------------------------------------------
template<int EPI, int BN>
__global__ __launch_bounds__(256) void gemm_glds(
    const unsigned short* __restrict__ A, const unsigned short* __restrict__ Bt,
    const float* __restrict__ bias, void* __restrict__ Cp,
    unsigned short* __restrict__ vtp, int M, int N, int K) {
    constexpr int NI = BN / 32;
    __shared__ __align__(16) unsigned short Al[128 * 64];
    __shared__ __align__(16) unsigned short Bl[BN * 64];

    const int tid  = threadIdx.x;
    const int lane = tid & 63;
    const int w    = tid >> 6;
    const int c16  = lane & 15;
    const int quad = lane >> 4;
    const int NT  = N / BN;
    const int pe  = NT >> 3;
    const int xcd = blockIdx.x & 7;
    const int ii  = blockIdx.x >> 3;
    const int n0  = (xcd * pe + ii % pe) * BN;
    const int m0  = (ii / pe) * 128;
    const int wm = (w >> 1) * 64;
    const int wn = (w & 1) * (BN / 2);

    floatx4 acc[4][NI] = {};

    const int srow = lane >> 3;
    const int sch  = ((lane & 7) ^ srow) * 8;
    const unsigned short* ag = A + (size_t)(m0 + w * 32 + srow) * K + sch;
    const unsigned short* bg = Bt + (size_t)(n0 + w * (BN / 4) + srow) * K + sch;

    const int s7 = c16 & 7;

    for (int k0 = 0; k0 < K; k0 += 64) {
        __syncthreads();
#pragma unroll
        for (int i = 0; i < 4; i++)
            glds16(ag + k0 + (size_t)(i * 8) * K, &Al[(w * 32 + i * 8) * 64]);
#pragma unroll
        for (int i = 0; i < BN / 32; i++)
            glds16(bg + k0 + (size_t)(i * 8) * K,
                   &Bl[(w * (BN / 4) + i * 8) * 64]);
        __syncthreads();

        short8 af[4][2], bf[NI][2];
#pragma unroll
        for (int im = 0; im < 4; im++)
#pragma unroll
            for (int kk = 0; kk < 2; kk++)
                af[im][kk] = *reinterpret_cast<const short8*>(
                    &Al[(wm + im * 16 + c16) * 64 + ((kk * 4 + quad) ^ s7) * 8]);
#pragma unroll
        for (int in = 0; in < NI; in++)
#pragma unroll
            for (int kk = 0; kk < 2; kk++)
                bf[in][kk] = *reinterpret_cast<const short8*>(
                    &Bl[(wn + in * 16 + c16) * 64 + ((kk * 4 + quad) ^ s7) * 8]);
#pragma unroll
        for (int im = 0; im < 4; im++)
#pragma unroll
            for (int in = 0; in < NI; in++)
#pragma unroll
                for (int kk = 0; kk < 2; kk++)
                    acc[im][in] = __builtin_amdgcn_mfma_f32_16x16x32_bf16(
                        af[im][kk], bf[in][kk], acc[im][in], 0, 0, 0);
    }

    const int ncol = n0 + wn;
    float bv[NI];
#pragma unroll
    for (int in = 0; in < NI; in++) bv[in] = bias[ncol + in * 16 + c16];

    if (EPI == 0) {
        float* C = (float*)Cp;
#pragma unroll
        for (int im = 0; im < 4; im++)
#pragma unroll
            for (int r = 0; r < 4; r++) {
                int row = m0 + wm + im * 16 + quad * 4 + r;
#pragma unroll
                for (int in = 0; in < NI; in++)
                    C[(size_t)row * N + ncol + in * 16 + c16] =
                        acc[im][in][r] + bv[in];
            }
    } else {
        if (ncol < 2 * C_) {
            const float fac = (ncol < C_) ? QSCALE : 1.0f;
            unsigned short* qkp = (unsigned short*)Cp;
#pragma unroll
            for (int im = 0; im < 4; im++)
#pragma unroll
                for (int r = 0; r < 4; r++) {
                    int row = m0 + wm + im * 16 + quad * 4 + r;
#pragma unroll
                    for (int in = 0; in < NI; in++)
                        qkp[(size_t)row * QK2_ + ncol + in * 16 + c16] =
                            f2b((acc[im][in][r] + bv[in]) * fac);
                }
        } else {                 // V -> vt[B,H,64,T]
#pragma unroll
            for (int im = 0; im < 4; im++) {
                int row0 = m0 + wm + im * 16 + quad * 4;
                int b  = row0 >> 11;
                int t0 = row0 & (T_ - 1);
#pragma unroll
                for (int in = 0; in < NI; in++) {
                    int dfull = ncol - 2 * C_ + in * 16 + c16;
                    short4v sv;
#pragma unroll
                    for (int r = 0; r < 4; r++)
                        sv[r] = (short)f2b(acc[im][in][r] + bv[in]);
                    *reinterpret_cast<short4v*>(
                        &vtp[(((size_t)(b << 10) + dfull) << 11) + t0]) = sv;
                }
            }
        }
    }
}

// ---------------------------------------------------------------------------
// Repack K,V into fragment-major buffers. 1024 blocks = (bh 32) x (chunk 32),
// 256 thr. Per (bh,chunk) region = 4096 shorts (8KB) each for K and V.
//   K frag f = ws*4+sub*2+dhalf, lane ll=quad*16+c16, j=0..7:
//     K[key=chunk*64+ws*32+sub*16+c16][d=dhalf*32+quad*8+j]
//   V frag f = ws*4+dt, lane ll, j:
//     V[d=dt*16+c16][key=chunk*64+ws*32 + (j<4 ? quad*4+j : 16+quad*4+j-4)]
// Thread tid handles frag=tid>>5, lanes ll=(tid&31)*2, +1. Writes coalesced
// short8; reads 16B/8B granules (L2/L3-resident).
// ---------------------------------------------------------------------------
__global__ __launch_bounds__(256) void repack(
    const unsigned short* __restrict__ qk, const unsigned short* __restrict__ vt,
    unsigned short* __restrict__ kfb, unsigned short* __restrict__ vfb) {
    const int bh    = blockIdx.x >> 5;
    const int chunk = blockIdx.x & 31;
    const int b = bh >> 4, h = bh & 15;
    const int tid  = threadIdx.x;
    const int frag = tid >> 5;
    const int ll0  = (tid & 31) * 2;
    const size_t obase = ((size_t)(bh * 32 + chunk)) * 4096 + frag * 512;

    {   // K: frag = ws*4 + sub*2 + dhalf
        const int ws = frag >> 2, sub = (frag >> 1) & 1, dh = frag & 1;
#pragma unroll
        for (int e = 0; e < 2; e++) {
            const int ll = ll0 + e, quad = ll >> 4, c16 = ll & 15;
            const int key = chunk * 64 + ws * 32 + sub * 16 + c16;
            short8 v = *reinterpret_cast<const short8*>(
                qk + ((size_t)(b * T_ + key)) * QK2_ + C_ + h * HD_ +
                dh * 32 + quad * 8);
            *reinterpret_cast<short8*>(kfb + obase + ll * 8) = v;
        }
    }
    {   // V: frag = ws*4 + dt
        const int ws = frag >> 2, dt = frag & 3;
#pragma unroll
        for (int e = 0; e < 2; e++) {
            const int ll = ll0 + e, quad = ll >> 4, c16 = ll & 15;
            const int d = dt * 16 + c16;
            const unsigned short* src = vt + ((size_t)(bh * 64 + d)) * T_ +
                                        chunk * 64 + ws * 32 + quad * 4;
            short4v v0 = *reinterpret_cast<const short4v*>(src);
            short4v v1 = *reinterpret_cast<const short4v*>(src + 16);
            short8 o;
            o[0] = v0[0]; o[1] = v0[1]; o[2] = v0[2]; o[3] = v0[3];
            o[4] = v1[0]; o[5] = v1[1]; o[6] = v1[2]; o[7] = v1[3];
            *reinterpret_cast<short8*>(vfb + obase + ll * 8) = o;
        }
    }
}

// ---------------------------------------------------------------------------
// One 64-key chunk, one wave: key-half ws x this wave's 32 q rows.
// Fragment-major operands: 4 K b128 + 4 V b128, all COALESCED (lane*16B
// contiguous). Same math as round-8 (verified): S^T per 16-key sub; PV
// window {sub0:quad*4+r, sub1:+16}; l via ones-MFMA.
// ---------------------------------------------------------------------------
#define ATTN_CHUNK(MASKED, kb, kcp, vcp)                                      \
{                                                                             \
    short8 kf00 = *reinterpret_cast<const short8*>((kcp));                    \
    short8 kf01 = *reinterpret_cast<const short8*>((kcp) + 512);              \
    short8 kf10 = *reinterpret_cast<const short8*>((kcp) + 1024);             \
    short8 kf11 = *reinterpret_cast<const short8*>((kcp) + 1536);             \
    short8 vf[4];                                                             \
    _Pragma("unroll")                                                         \
    for (int dt = 0; dt < 4; dt++)                                            \
        vf[dt] = *reinterpret_cast<const short8*>((vcp) + dt * 512);          \
    short8 pf[2];                                                             \
    _Pragma("unroll")                                                         \
    for (int qt = 0; qt < 2; qt++) {                                          \
        floatx4 s0 = __builtin_amdgcn_mfma_f32_16x16x32_bf16(                 \
            kf00, af[qt][0], z, 0, 0, 0);                                     \
        s0 = __builtin_amdgcn_mfma_f32_16x16x32_bf16(                         \
            kf01, af[qt][1], s0, 0, 0, 0);                                    \
        floatx4 s1 = __builtin_amdgcn_mfma_f32_16x16x32_bf16(                 \
            kf10, af[qt][0], z, 0, 0, 0);                                     \
        s1 = __builtin_amdgcn_mfma_f32_16x16x32_bf16(                         \
            kf11, af[qt][1], s1, 0, 0, 0);                                    \
        short8 p8;                                                            \
        _Pragma("unroll")                                                     \
        for (int r = 0; r < 4; r++) {                                         \
            float p0, p1;                                                     \
            if (MASKED) {                                                     \
                int key0 = (kb) + ws * 32 + quad * 4 + r;                     \
                int qr = q0 + wq * 32 + qt * 16 + c16;                        \
                p0 = (key0 <= qr) ? fexp2(s0[r]) : 0.f;                       \
                p1 = (key0 + 16 <= qr) ? fexp2(s1[r]) : 0.f;                  \
            } else {                                                          \
                p0 = fexp2(s0[r]);                                            \
                p1 = fexp2(s1[r]);                                            \
            }                                                                 \
            p8[r] = (short)f2b(p0);                                           \
            p8[4 + r] = (short)f2b(p1);                                       \
        }                                                                     \
        pf[qt] = p8;                                                          \
    }                                                                         \
    _Pragma("unroll")                                                         \
    for (int qt = 0; qt < 2; qt++)                                            \
        O1[qt] = __builtin_amdgcn_mfma_f32_16x16x32_bf16(                     \
            pf[qt], ones, O1[qt], 0, 0, 0);                                   \
    _Pragma("unroll")                                                         \
    for (int dt = 0; dt < 4; dt++)                                            \
        _Pragma("unroll")                                                     \
        for (int qt = 0; qt < 2; qt++)                                        \
            O[qt][dt] = __builtin_amdgcn_mfma_f32_16x16x32_bf16(              \
                pf[qt], vf[dt], O[qt][dt], 0, 0, 0);                          \
}

// ---------------------------------------------------------------------------
// Flash attention, 2x2 wave split, zero-LDS main loop, fragment-major K/V.
// Block = 256 thr = 4 waves; block t owns Q rows [64t,64t+64), nch=t+1,
// LPT. Wave w: q-half wq=w&1 (Q in regs), key-half ws=w>>1. No barriers in
// the loop. Pair merge through 20KB LDS (one barrier). All O/O1 indices
// compile-time (rule #20). Fully-masked {wq0,ws1} diagonal corner skipped.
// launch_bounds(256,3): VGPR cap ~170 — round-8-verified spill-free
// (natural usage ~60; runtime occupancy then up to 8 blocks/CU).
// DO NOT tighten this cap (round-9: cap 84 -> 314MB spill).
// ---------------------------------------------------------------------------
__global__ __launch_bounds__(256, 3) void attn_mfma(
    const unsigned short* __restrict__ qk,
    const unsigned short* __restrict__ kfb,
    const unsigned short* __restrict__ vfb,
    unsigned short* __restrict__ y) {
    __shared__ __align__(16) float Of[4096];   // [wq][qt][dt][lane][4]
    __shared__ __align__(16) float Lb[1024];   // [wq][qt][lane][4] (O1 park)

    const int tid  = threadIdx.x;
    const int lane = tid & 63;
    const int w    = tid >> 6;          // 0..3
    const int wq   = w & 1;             // q-half
    const int ws   = w >> 1;            // key-half
    const int c16  = lane & 15;
    const int quad = lane >> 4;
    const int bh = blockIdx.x & 31;
    const int t  = 31 - (blockIdx.x >> 5);   // longest-first
    const int b  = bh >> 4;
    const int h  = bh & 15;
    const int q0 = t * 64;
    const int nch = t + 1;

    const unsigned short* qrow = qk + (size_t)b * T_ * QK2_ + h * HD_;
    const unsigned short* kfp = kfb + ((size_t)bh * 32) * 4096 + ws * 2048 + lane * 8;
    const unsigned short* vfp = vfb + ((size_t)bh * 32) * 4096 + ws * 2048 + lane * 8;

    // Q in registers: af[qt][hh] = Q[q0+wq*32+qt*16+c16][hh*32+quad*8 ..+8]
    short8 af[2][2];
#pragma unroll
    for (int qt = 0; qt < 2; qt++)
#pragma unroll
        for (int hh = 0; hh < 2; hh++)
            af[qt][hh] = *reinterpret_cast<const short8*>(
                qrow + (size_t)(q0 + wq * 32 + qt * 16 + c16) * QK2_ +
                hh * 32 + quad * 8);

    floatx4 O[2][4] = {};
    floatx4 O1[2] = {};                  // row-sums l via ones-MFMA
    const floatx4 z = {0.f, 0.f, 0.f, 0.f};
    short8 ones;
#pragma unroll
    for (int j = 0; j < 8; j++) ones[j] = (short)0x3F80;   // bf16 1.0

    for (int c = 0; c < nch; c++) {
        const int kb = c * 64;
        const unsigned short* kcp = kfp + (size_t)c * 4096;
        const unsigned short* vcp = vfp + (size_t)c * 4096;
        if (c + 1 < nch) {
            ATTN_CHUNK(0, kb, kcp, vcp)
        } else if (!(wq == 0 && ws == 1)) {
            // diagonal chunk; {wq0,ws1} corner is fully masked -> skip
            ATTN_CHUNK(1, kb, kcp, vcp)
        }
    }

    // ---- pair merge: O_total = O(ws=0) + O(ws=1) per q-half.
    // ws=1 parks O (32 f32/lane) + O1 in LDS; ws=0 partners add and write.
    if (ws) {
#pragma unroll
        for (int qt = 0; qt < 2; qt++) {
#pragma unroll
            for (int dt = 0; dt < 4; dt++)
                *reinterpret_cast<floatx4*>(
                    &Of[wq * 2048 + qt * 1024 + dt * 256 + lane * 4]) = O[qt][dt];
            *reinterpret_cast<floatx4*>(
                &Lb[wq * 512 + qt * 256 + lane * 4]) = O1[qt];
        }
    }
    __syncthreads();
    if (ws == 0) {
#pragma unroll
        for (int qt = 0; qt < 2; qt++) {
#pragma unroll
            for (int dt = 0; dt < 4; dt++)
                O[qt][dt] += *reinterpret_cast<const floatx4*>(
                    &Of[wq * 2048 + qt * 1024 + dt * 256 + lane * 4]);
            floatx4 lr = O1[qt] + *reinterpret_cast<const floatx4*>(
                    &Lb[wq * 512 + qt * 256 + lane * 4]);

            // write rows q0+wq*32+qt*16+quad*4+r, cols h*HD+dt*16+c16
#pragma unroll
            for (int dt = 0; dt < 4; dt++)
#pragma unroll
                for (int r = 0; r < 4; r++) {
                    float val = O[qt][dt][r] / fmaxf(lr[r], 1e-30f);
                    y[((size_t)b * T_ + q0 + wq * 32 + qt * 16 + quad * 4 + r)
                          * C_ + h * HD_ + dt * 16 + c16] = f2b(val);
                }
        }
    }
}

extern "C" void kernel_launch(void* const* d_in, const int* in_sizes, int n_in,
                              void* d_out, int out_size, void* d_ws, size_t ws_size,
                              hipStream_t stream) {
    const float* x     = (const float*)d_in[0];
    const float* w_qkv = (const float*)d_in[1];
    const float* b_qkv = (const float*)d_in[2];
    const float* w_out = (const float*)d_in[3];
    const float* b_out = (const float*)d_in[4];
    float* out = (float*)d_out;

    unsigned short* qkb = (unsigned short*)d_ws;                 // [4096][2048]
    unsigned short* vtb = qkb + (size_t)M_ * QK2_;               // [B,H,64,T]
    unsigned short* yb  = vtb + (size_t)B_ * H_ * HD_ * T_;      // [4096][1024]
    unsigned short* wt1 = yb + (size_t)M_ * C_;                  // [3072][1024]
    unsigned short* wt2 = wt1 + (size_t)N3_ * C_;                // [1024][1024]
    unsigned short* xb  = wt2 + (size_t)C_ * C_;                 // [4096][1024]
    unsigned short* kfb = xb + (size_t)M_ * C_;                  // [32*32][4096]
    unsigned short* vfb = kfb + (size_t)32 * 32 * 4096;          // [32*32][4096]

    prep<<<4096 + 1536 + 512, 256, 0, stream>>>(x, w_qkv, w_out, xb, wt1, wt2);

    gemm_glds<1, 128><<<(N3_ / 128) * (M_ / 128), 256, 0, stream>>>(
        xb, wt1, b_qkv, qkb, vtb, M_, N3_, C_);

    repack<<<32 * 32, 256, 0, stream>>>(qkb, vtb, kfb, vfb);

    attn_mfma<<<B_ * H_ * 32, 256, 0, stream>>>(qkb, kfb, vfb, yb);

    gemm_glds<0, 64><<<(C_ / 64) * (M_ / 128), 256, 0, stream>>>(
        yb, wt2, b_out, out, nullptr, M_, C_, C_);
}

// Round 11
// 172.170 us; speedup vs baseline: 1.8331x; 1.0446x over previous
//
#include <hip/hip_runtime.h>
#include <hip/hip_bf16.h>

// B=2, T=2048, C=1024, H=16, HD=64. f32 I/O; bf16 MFMA internally, f32 accum.
//
//   0) prep (fused): x -> xb bf16; w_qkv,w_out -> bf16 W^T[N][K]
//   1) gemm_glds<EPI=1,BN=128>: qkv proj. Epilogue writes THREE layouts:
//      Q (scaled 0.125*log2e) -> qb[4096][1024]; K -> kfb FRAGMENT-MAJOR;
//      V -> vfb FRAGMENT-MAJOR. (Round-11: repack kernel fused away — V
//      frag write is the same single 8B store as the old vt write; K frag
//      write improves 4KB-stride scatter to 4x2B within one 64B line.)
//   2) attn_mfma: flash attention, static exp2 softmax, 2x2 wave split
//      (round-7 verified): wave w = q-half wq=w&1 x key-half ws=w>>1; P
//      feeds PV A-frag directly from registers; l via ones-MFMA (round-8
//      verified). ZERO-LDS main loop, no barriers; K = 4 coalesced b128,
//      V = 4 coalesced b128 per chunk from kfb/vfb (round-10 verified:
//      attn < 42us, spill-free). Pair merge through 20KB LDS (one
//      barrier). All O/O1 indices compile-time (rule #20).
//      launch_bounds(256,3): cap ~170, verified spill-free. DO NOT
//      tighten (round-9: cap 84 -> 314MB spill).
//   3) gemm_glds<EPI=0,BN=64>: out proj -> d_out f32

#define B_ 2
#define T_ 2048
#define C_ 1024
#define H_ 16
#define HD_ 64
#define M_ (B_ * T_)      // 4096
#define N3_ (3 * C_)      // 3072
#define QSCALE 0.18033688f   // 0.125 * log2(e)

typedef __attribute__((ext_vector_type(8))) short short8;
typedef __attribute__((ext_vector_type(4))) short short4v;
typedef __attribute__((ext_vector_type(4))) float floatx4;

__device__ __forceinline__ unsigned short f2b(float f) {
    __hip_bfloat16 h = __float2bfloat16(f);
    return *reinterpret_cast<unsigned short*>(&h);
}

__device__ __forceinline__ float fexp2(float x) {
#if __has_builtin(__builtin_amdgcn_exp2f)
    return __builtin_amdgcn_exp2f(x);
#else
    return exp2f(x);
#endif
}

__device__ __forceinline__ void glds16(const void* g, void* l) {
    __builtin_amdgcn_global_load_lds(
        (const __attribute__((address_space(1))) void*)g,
        (__attribute__((address_space(3))) void*)l, 16, 0, 0);
}

// ---------------------------------------------------------------------------
// Fused prep. seg0 (4096 blocks): x f32->bf16. seg1 (1536): w_qkv -> wt1
// [3072][1024] via 64(k)x32(n) tiles, short8 coalesced writes. seg2 (512):
// w_out -> wt2.
// ---------------------------------------------------------------------------
__global__ __launch_bounds__(256) void prep(
    const float* __restrict__ x, const float* __restrict__ w_qkv,
    const float* __restrict__ w_out, unsigned short* __restrict__ xb,
    unsigned short* __restrict__ wt1, unsigned short* __restrict__ wt2) {
    __shared__ float t[64][33];
    const int bi = blockIdx.x;
    const int tid = threadIdx.x;
    if (bi < 4096) {
        int i = (bi * 256 + tid) * 4;
        float4 v = *reinterpret_cast<const float4*>(x + i);
        short4v s;
        s[0] = (short)f2b(v.x); s[1] = (short)f2b(v.y);
        s[2] = (short)f2b(v.z); s[3] = (short)f2b(v.w);
        *reinterpret_cast<short4v*>(xb + i) = s;
        return;
    }
    const float* src; unsigned short* dst; int n0, k0, N;
    if (bi < 4096 + 1536) {
        int u = bi - 4096;
        src = w_qkv; dst = wt1; N = N3_;
        k0 = (u & 15) * 64; n0 = (u >> 4) * 32;
    } else {
        int u = bi - (4096 + 1536);
        src = w_out; dst = wt2; N = C_;
        k0 = (u & 15) * 64; n0 = (u >> 4) * 32;
    }
    const int tx = tid & 31, ty = tid >> 5;
#pragma unroll
    for (int i = 0; i < 8; i++)
        t[ty + i * 8][tx] = src[(size_t)(k0 + ty + i * 8) * N + n0 + tx];
    __syncthreads();
    const int row = tid >> 3;
    const int kp  = (tid & 7) * 8;
    short8 o;
#pragma unroll
    for (int j = 0; j < 8; j++) o[j] = (short)f2b(t[kp + j][row]);
    *reinterpret_cast<short8*>(&dst[(size_t)(n0 + row) * C_ + k0 + kp]) = o;
}

// ---------------------------------------------------------------------------
// GEMM: C[M,N] = A[M,K] @ Bt^T[N,K] + bias[N]. A,Bt bf16. Tile 128 x BN,
// BK=64, 4 waves 2x2. LDS rows 64 shorts, XOR chunk swizzle; glds16 staging.
// 1D grid, XCD-banded. EPI=1 epilogue: Q->qb (stride C_, scaled), K->kfbp
// fragment-major, V->vfbp fragment-major (see attn frag definitions).
// ---------------------------------------------------------------------------
template<int EPI, int BN>
__global__ __launch_bounds__(256) void gemm_glds(
    const unsigned short* __restrict__ A, const unsigned short* __restrict__ Bt,
    const float* __restrict__ bias, void* __restrict__ Cp,
    unsigned short* __restrict__ kfbp, unsigned short* __restrict__ vfbp,
    int M, int N, int K) {
    constexpr int NI = BN / 32;
    __shared__ __align__(16) unsigned short Al[128 * 64];
    __shared__ __align__(16) unsigned short Bl[BN * 64];

    const int tid  = threadIdx.x;
    const int lane = tid & 63;
    const int w    = tid >> 6;
    const int c16  = lane & 15;
    const int quad = lane >> 4;
    const int NT  = N / BN;
    const int pe  = NT >> 3;
    const int xcd = blockIdx.x & 7;
    const int ii  = blockIdx.x >> 3;
    const int n0  = (xcd * pe + ii % pe) * BN;
    const int m0  = (ii / pe) * 128;
    const int wm = (w >> 1) * 64;
    const int wn = (w & 1) * (BN / 2);

    floatx4 acc[4][NI] = {};

    const int srow = lane >> 3;
    const int sch  = ((lane & 7) ^ srow) * 8;
    const unsigned short* ag = A + (size_t)(m0 + w * 32 + srow) * K + sch;
    const unsigned short* bg = Bt + (size_t)(n0 + w * (BN / 4) + srow) * K + sch;

    const int s7 = c16 & 7;

    for (int k0 = 0; k0 < K; k0 += 64) {
        __syncthreads();
#pragma unroll
        for (int i = 0; i < 4; i++)
            glds16(ag + k0 + (size_t)(i * 8) * K, &Al[(w * 32 + i * 8) * 64]);
#pragma unroll
        for (int i = 0; i < BN / 32; i++)
            glds16(bg + k0 + (size_t)(i * 8) * K,
                   &Bl[(w * (BN / 4) + i * 8) * 64]);
        __syncthreads();

        short8 af[4][2], bf[NI][2];
#pragma unroll
        for (int im = 0; im < 4; im++)
#pragma unroll
            for (int kk = 0; kk < 2; kk++)
                af[im][kk] = *reinterpret_cast<const short8*>(
                    &Al[(wm + im * 16 + c16) * 64 + ((kk * 4 + quad) ^ s7) * 8]);
#pragma unroll
        for (int in = 0; in < NI; in++)
#pragma unroll
            for (int kk = 0; kk < 2; kk++)
                bf[in][kk] = *reinterpret_cast<const short8*>(
                    &Bl[(wn + in * 16 + c16) * 64 + ((kk * 4 + quad) ^ s7) * 8]);
#pragma unroll
        for (int im = 0; im < 4; im++)
#pragma unroll
            for (int in = 0; in < NI; in++)
#pragma unroll
                for (int kk = 0; kk < 2; kk++)
                    acc[im][in] = __builtin_amdgcn_mfma_f32_16x16x32_bf16(
                        af[im][kk], bf[in][kk], acc[im][in], 0, 0, 0);
    }

    const int ncol = n0 + wn;
    float bv[NI];
#pragma unroll
    for (int in = 0; in < NI; in++) bv[in] = bias[ncol + in * 16 + c16];

    if (EPI == 0) {
        float* C = (float*)Cp;
#pragma unroll
        for (int im = 0; im < 4; im++)
#pragma unroll
            for (int r = 0; r < 4; r++) {
                int row = m0 + wm + im * 16 + quad * 4 + r;
#pragma unroll
                for (int in = 0; in < NI; in++)
                    C[(size_t)row * N + ncol + in * 16 + c16] =
                        acc[im][in][r] + bv[in];
            }
    } else {
        if (ncol < C_) {                 // Q -> qb[4096][1024], pre-scaled
            unsigned short* qb = (unsigned short*)Cp;
#pragma unroll
            for (int im = 0; im < 4; im++)
#pragma unroll
                for (int r = 0; r < 4; r++) {
                    int row = m0 + wm + im * 16 + quad * 4 + r;
#pragma unroll
                    for (int in = 0; in < NI; in++)
                        qb[(size_t)row * C_ + ncol + in * 16 + c16] =
                            f2b((acc[im][in][r] + bv[in]) * QSCALE);
                }
        } else if (ncol < 2 * C_) {      // K -> kfb fragment-major
            // frag = ws*4+sub*2+dh; lane ll=(quad_d,c16_k); elem j = d&7.
            // 4 consecutive keys (r) -> ll..ll+3: 4x2B stores in one 64B line.
#pragma unroll
            for (int im = 0; im < 4; im++) {
                int row0 = m0 + wm + im * 16 + quad * 4;   // token base (%4==0)
                int b    = row0 >> 11;
                int key  = row0 & (T_ - 1);
                int chunk = key >> 6;
                int kk    = key & 63;
                int wsd   = kk >> 5;
                int subd  = (kk >> 4) & 1;
                int c16d  = kk & 15;
#pragma unroll
                for (int in = 0; in < NI; in++) {
                    int dfull = ncol - C_ + in * 16 + c16;
                    int hh = dfull >> 6;
                    int d  = dfull & 63;
                    size_t base =
                        ((size_t)((b * 16 + hh) * 32 + chunk)) * 4096 +
                        (wsd * 4 + subd * 2 + (d >> 5)) * 512 +
                        (((d >> 3) & 3) * 16 + c16d) * 8 + (d & 7);
#pragma unroll
                    for (int r = 0; r < 4; r++)
                        kfbp[base + (size_t)r * 8] =
                            f2b(acc[im][in][r] + bv[in]);
                }
            }
        } else {                         // V -> vfb fragment-major
            // frag = ws*4+dt; lane ll=(quad_k,c16_d); 4 keys -> contiguous
            // j = jb..jb+3: one 8B short4v store (same count as old vt).
#pragma unroll
            for (int im = 0; im < 4; im++) {
                int row0 = m0 + wm + im * 16 + quad * 4;
                int b    = row0 >> 11;
                int key  = row0 & (T_ - 1);
                int chunk = key >> 6;
                int kk    = key & 63;
                int wsd   = kk >> 5;
                int qd    = (kk >> 2) & 3;
                int jb    = (kk & 16) ? 4 : 0;
#pragma unroll
                for (int in = 0; in < NI; in++) {
                    int dfull = ncol - 2 * C_ + in * 16 + c16;
                    int hh = dfull >> 6;
                    int d  = dfull & 63;
                    short4v sv;
#pragma unroll
                    for (int r = 0; r < 4; r++)
                        sv[r] = (short)f2b(acc[im][in][r] + bv[in]);
                    *reinterpret_cast<short4v*>(
                        &vfbp[((size_t)((b * 16 + hh) * 32 + chunk)) * 4096 +
                              (wsd * 4 + (d >> 4)) * 512 +
                              (qd * 16 + (d & 15)) * 8 + jb]) = sv;
                }
            }
        }
    }
}

// ---------------------------------------------------------------------------
// One 64-key chunk, one wave: key-half ws x this wave's 32 q rows.
// Fragment-major operands: 4 K b128 + 4 V b128, all COALESCED (lane*16B
// contiguous). Same math as round-8 (verified): S^T per 16-key sub; PV
// window {sub0:quad*4+r, sub1:+16}; l via ones-MFMA.
// ---------------------------------------------------------------------------
#define ATTN_CHUNK(MASKED, kb, kcp, vcp)                                      \
{                                                                             \
    short8 kf00 = *reinterpret_cast<const short8*>((kcp));                    \
    short8 kf01 = *reinterpret_cast<const short8*>((kcp) + 512);              \
    short8 kf10 = *reinterpret_cast<const short8*>((kcp) + 1024);             \
    short8 kf11 = *reinterpret_cast<const short8*>((kcp) + 1536);             \
    short8 vf[4];                                                             \
    _Pragma("unroll")                                                         \
    for (int dt = 0; dt < 4; dt++)                                            \
        vf[dt] = *reinterpret_cast<const short8*>((vcp) + dt * 512);          \
    short8 pf[2];                                                             \
    _Pragma("unroll")                                                         \
    for (int qt = 0; qt < 2; qt++) {                                          \
        floatx4 s0 = __builtin_amdgcn_mfma_f32_16x16x32_bf16(                 \
            kf00, af[qt][0], z, 0, 0, 0);                                     \
        s0 = __builtin_amdgcn_mfma_f32_16x16x32_bf16(                         \
            kf01, af[qt][1], s0, 0, 0, 0);                                    \
        floatx4 s1 = __builtin_amdgcn_mfma_f32_16x16x32_bf16(                 \
            kf10, af[qt][0], z, 0, 0, 0);                                     \
        s1 = __builtin_amdgcn_mfma_f32_16x16x32_bf16(                         \
            kf11, af[qt][1], s1, 0, 0, 0);                                    \
        short8 p8;                                                            \
        _Pragma("unroll")                                                     \
        for (int r = 0; r < 4; r++) {                                         \
            float p0, p1;                                                     \
            if (MASKED) {                                                     \
                int key0 = (kb) + ws * 32 + quad * 4 + r;                     \
                int qr = q0 + wq * 32 + qt * 16 + c16;                        \
                p0 = (key0 <= qr) ? fexp2(s0[r]) : 0.f;                       \
                p1 = (key0 + 16 <= qr) ? fexp2(s1[r]) : 0.f;                  \
            } else {                                                          \
                p0 = fexp2(s0[r]);                                            \
                p1 = fexp2(s1[r]);                                            \
            }                                                                 \
            p8[r] = (short)f2b(p0);                                           \
            p8[4 + r] = (short)f2b(p1);                                       \
        }                                                                     \
        pf[qt] = p8;                                                          \
    }                                                                         \
    _Pragma("unroll")                                                         \
    for (int qt = 0; qt < 2; qt++)                                            \
        O1[qt] = __builtin_amdgcn_mfma_f32_16x16x32_bf16(                     \
            pf[qt], ones, O1[qt], 0, 0, 0);                                   \
    _Pragma("unroll")                                                         \
    for (int dt = 0; dt < 4; dt++)                                            \
        _Pragma("unroll")                                                     \
        for (int qt = 0; qt < 2; qt++)                                        \
            O[qt][dt] = __builtin_amdgcn_mfma_f32_16x16x32_bf16(              \
                pf[qt], vf[dt], O[qt][dt], 0, 0, 0);                          \
}

// ---------------------------------------------------------------------------
// Flash attention, 2x2 wave split, zero-LDS main loop, fragment-major K/V.
// Block = 256 thr = 4 waves; block t owns Q rows [64t,64t+64), nch=t+1,
// LPT. Wave w: q-half wq=w&1 (Q in regs, from qb stride C_), key-half
// ws=w>>1. No barriers in the loop. Pair merge through 20KB LDS (one
// barrier). All O/O1 indices compile-time (rule #20). Fully-masked
// {wq0,ws1} diagonal corner skipped. launch_bounds(256,3): cap ~170,
// round-8/10-verified spill-free. DO NOT tighten (round-9: cap 84 ->
// 314MB spill).
// ---------------------------------------------------------------------------
__global__ __launch_bounds__(256, 3) void attn_mfma(
    const unsigned short* __restrict__ qk,
    const unsigned short* __restrict__ kfb,
    const unsigned short* __restrict__ vfb,
    unsigned short* __restrict__ y) {
    __shared__ __align__(16) float Of[4096];   // [wq][qt][dt][lane][4]
    __shared__ __align__(16) float Lb[1024];   // [wq][qt][lane][4] (O1 park)

    const int tid  = threadIdx.x;
    const int lane = tid & 63;
    const int w    = tid >> 6;          // 0..3
    const int wq   = w & 1;             // q-half
    const int ws   = w >> 1;            // key-half
    const int c16  = lane & 15;
    const int quad = lane >> 4;
    const int bh = blockIdx.x & 31;
    const int t  = 31 - (blockIdx.x >> 5);   // longest-first
    const int b  = bh >> 4;
    const int h  = bh & 15;
    const int q0 = t * 64;
    const int nch = t + 1;

    const unsigned short* qrow = qk + (size_t)b * T_ * C_ + h * HD_;
    const unsigned short* kfp = kfb + ((size_t)bh * 32) * 4096 + ws * 2048 + lane * 8;
    const unsigned short* vfp = vfb + ((size_t)bh * 32) * 4096 + ws * 2048 + lane * 8;

    // Q in registers: af[qt][hh] = Q[q0+wq*32+qt*16+c16][hh*32+quad*8 ..+8]
    short8 af[2][2];
#pragma unroll
    for (int qt = 0; qt < 2; qt++)
#pragma unroll
        for (int hh = 0; hh < 2; hh++)
            af[qt][hh] = *reinterpret_cast<const short8*>(
                qrow + (size_t)(q0 + wq * 32 + qt * 16 + c16) * C_ +
                hh * 32 + quad * 8);

    floatx4 O[2][4] = {};
    floatx4 O1[2] = {};                  // row-sums l via ones-MFMA
    const floatx4 z = {0.f, 0.f, 0.f, 0.f};
    short8 ones;
#pragma unroll
    for (int j = 0; j < 8; j++) ones[j] = (short)0x3F80;   // bf16 1.0

    for (int c = 0; c < nch; c++) {
        const int kb = c * 64;
        const unsigned short* kcp = kfp + (size_t)c * 4096;
        const unsigned short* vcp = vfp + (size_t)c * 4096;
        if (c + 1 < nch) {
            ATTN_CHUNK(0, kb, kcp, vcp)
        } else if (!(wq == 0 && ws == 1)) {
            // diagonal chunk; {wq0,ws1} corner is fully masked -> skip
            ATTN_CHUNK(1, kb, kcp, vcp)
        }
    }

    // ---- pair merge: O_total = O(ws=0) + O(ws=1) per q-half.
    // ws=1 parks O (32 f32/lane) + O1 in LDS; ws=0 partners add and write.
    if (ws) {
#pragma unroll
        for (int qt = 0; qt < 2; qt++) {
#pragma unroll
            for (int dt = 0; dt < 4; dt++)
                *reinterpret_cast<floatx4*>(
                    &Of[wq * 2048 + qt * 1024 + dt * 256 + lane * 4]) = O[qt][dt];
            *reinterpret_cast<floatx4*>(
                &Lb[wq * 512 + qt * 256 + lane * 4]) = O1[qt];
        }
    }
    __syncthreads();
    if (ws == 0) {
#pragma unroll
        for (int qt = 0; qt < 2; qt++) {
#pragma unroll
            for (int dt = 0; dt < 4; dt++)
                O[qt][dt] += *reinterpret_cast<const floatx4*>(
                    &Of[wq * 2048 + qt * 1024 + dt * 256 + lane * 4]);
            floatx4 lr = O1[qt] + *reinterpret_cast<const floatx4*>(
                    &Lb[wq * 512 + qt * 256 + lane * 4]);

            // write rows q0+wq*32+qt*16+quad*4+r, cols h*HD+dt*16+c16
#pragma unroll
            for (int dt = 0; dt < 4; dt++)
#pragma unroll
                for (int r = 0; r < 4; r++) {
                    float val = O[qt][dt][r] / fmaxf(lr[r], 1e-30f);
                    y[((size_t)b * T_ + q0 + wq * 32 + qt * 16 + quad * 4 + r)
                          * C_ + h * HD_ + dt * 16 + c16] = f2b(val);
                }
        }
    }
}

extern "C" void kernel_launch(void* const* d_in, const int* in_sizes, int n_in,
                              void* d_out, int out_size, void* d_ws, size_t ws_size,
                              hipStream_t stream) {
    const float* x     = (const float*)d_in[0];
    const float* w_qkv = (const float*)d_in[1];
    const float* b_qkv = (const float*)d_in[2];
    const float* w_out = (const float*)d_in[3];
    const float* b_out = (const float*)d_in[4];
    float* out = (float*)d_out;

    unsigned short* qb  = (unsigned short*)d_ws;                 // [4096][1024]
    unsigned short* kfb = qb + (size_t)M_ * C_;                  // [32*32][4096]
    unsigned short* vfb = kfb + (size_t)32 * 32 * 4096;          // [32*32][4096]
    unsigned short* yb  = vfb + (size_t)32 * 32 * 4096;          // [4096][1024]
    unsigned short* wt1 = yb + (size_t)M_ * C_;                  // [3072][1024]
    unsigned short* wt2 = wt1 + (size_t)N3_ * C_;                // [1024][1024]
    unsigned short* xb  = wt2 + (size_t)C_ * C_;                 // [4096][1024]

    prep<<<4096 + 1536 + 512, 256, 0, stream>>>(x, w_qkv, w_out, xb, wt1, wt2);

    gemm_glds<1, 128><<<(N3_ / 128) * (M_ / 128), 256, 0, stream>>>(
        xb, wt1, b_qkv, qb, kfb, vfb, M_, N3_, C_);

    attn_mfma<<<B_ * H_ * 32, 256, 0, stream>>>(qb, kfb, vfb, yb);

    gemm_glds<0, 64><<<(C_ / 64) * (M_ / 128), 256, 0, stream>>>(
        yb, wt2, b_out, out, nullptr, nullptr, M_, C_, C_);
}

// Round 12
// 161.431 us; speedup vs baseline: 1.9551x; 1.0665x over previous
//
#include <hip/hip_runtime.h>
#include <hip/hip_bf16.h>

// B=2, T=2048, C=1024, H=16, HD=64. f32 I/O; bf16 MFMA internally, f32 accum.
//
//   0) prep (fused): x -> xb bf16 (8 floats/thread); w_qkv,w_out -> bf16
//      W^T[N][K].
//   1) gemm_glds<EPI=1,BN=128>: qkv proj. Epilogue writes THREE layouts:
//      Q (scaled 0.125*log2e) -> qb[4096][1024]; K -> kfb FRAGMENT-MAJOR;
//      V -> vfb FRAGMENT-MAJOR (round-11 verified, repack fused away).
//   2) attn_mfma: flash attention, static exp2 softmax, 2x2 wave split;
//      P feeds PV A-frag directly from registers; l via ones-MFMA;
//      ZERO-LDS main loop from fragment-major kfb/vfb (all verified).
//      ROUND-12: 2-deep register prefetch — loop 2-unrolled with NAMED
//      frag sets A/B (rule #20-safe); chunk c+1's 8 coalesced b128 loads
//      issue before chunk c's compute, hiding ~200cyc L2 latency inside
//      the wave (was TLP-only). launch_bounds(256,2) -> VGPR cap 256 so
//      the +64-reg double-buffer CANNOT spill (rounds 5/6/9: est. runs
//      ~30 low; round-9: cap 84 -> 314MB spill).
//   3) gemm_glds<EPI=0,BN=64>: out proj -> d_out f32

#define B_ 2
#define T_ 2048
#define C_ 1024
#define H_ 16
#define HD_ 64
#define M_ (B_ * T_)      // 4096
#define N3_ (3 * C_)      // 3072
#define QSCALE 0.18033688f   // 0.125 * log2(e)

typedef __attribute__((ext_vector_type(8))) short short8;
typedef __attribute__((ext_vector_type(4))) short short4v;
typedef __attribute__((ext_vector_type(4))) float floatx4;

__device__ __forceinline__ unsigned short f2b(float f) {
    __hip_bfloat16 h = __float2bfloat16(f);
    return *reinterpret_cast<unsigned short*>(&h);
}

__device__ __forceinline__ float fexp2(float x) {
#if __has_builtin(__builtin_amdgcn_exp2f)
    return __builtin_amdgcn_exp2f(x);
#else
    return exp2f(x);
#endif
}

__device__ __forceinline__ void glds16(const void* g, void* l) {
    __builtin_amdgcn_global_load_lds(
        (const __attribute__((address_space(1))) void*)g,
        (__attribute__((address_space(3))) void*)l, 16, 0, 0);
}

// ---------------------------------------------------------------------------
// Fused prep. seg0 (2048 blocks): x f32->bf16, 8 floats/thread. seg1 (1536):
// w_qkv -> wt1 [3072][1024] via 64(k)x32(n) tiles, short8 coalesced writes.
// seg2 (512): w_out -> wt2.
// ---------------------------------------------------------------------------
__global__ __launch_bounds__(256) void prep(
    const float* __restrict__ x, const float* __restrict__ w_qkv,
    const float* __restrict__ w_out, unsigned short* __restrict__ xb,
    unsigned short* __restrict__ wt1, unsigned short* __restrict__ wt2) {
    __shared__ float t[64][33];
    const int bi = blockIdx.x;
    const int tid = threadIdx.x;
    if (bi < 2048) {
        int i = (bi * 256 + tid) * 8;
        float4 v0 = *reinterpret_cast<const float4*>(x + i);
        float4 v1 = *reinterpret_cast<const float4*>(x + i + 4);
        short8 s;
        s[0] = (short)f2b(v0.x); s[1] = (short)f2b(v0.y);
        s[2] = (short)f2b(v0.z); s[3] = (short)f2b(v0.w);
        s[4] = (short)f2b(v1.x); s[5] = (short)f2b(v1.y);
        s[6] = (short)f2b(v1.z); s[7] = (short)f2b(v1.w);
        *reinterpret_cast<short8*>(xb + i) = s;
        return;
    }
    const float* src; unsigned short* dst; int n0, k0, N;
    if (bi < 2048 + 1536) {
        int u = bi - 2048;
        src = w_qkv; dst = wt1; N = N3_;
        k0 = (u & 15) * 64; n0 = (u >> 4) * 32;
    } else {
        int u = bi - (2048 + 1536);
        src = w_out; dst = wt2; N = C_;
        k0 = (u & 15) * 64; n0 = (u >> 4) * 32;
    }
    const int tx = tid & 31, ty = tid >> 5;
#pragma unroll
    for (int i = 0; i < 8; i++)
        t[ty + i * 8][tx] = src[(size_t)(k0 + ty + i * 8) * N + n0 + tx];
    __syncthreads();
    const int row = tid >> 3;
    const int kp  = (tid & 7) * 8;
    short8 o;
#pragma unroll
    for (int j = 0; j < 8; j++) o[j] = (short)f2b(t[kp + j][row]);
    *reinterpret_cast<short8*>(&dst[(size_t)(n0 + row) * C_ + k0 + kp]) = o;
}

// ---------------------------------------------------------------------------
// GEMM: C[M,N] = A[M,K] @ Bt^T[N,K] + bias[N]. A,Bt bf16. Tile 128 x BN,
// BK=64, 4 waves 2x2. LDS rows 64 shorts, XOR chunk swizzle; glds16 staging.
// 1D grid, XCD-banded. EPI=1 epilogue: Q->qb (stride C_, scaled), K->kfbp
// fragment-major, V->vfbp fragment-major (see attn frag definitions).
// ---------------------------------------------------------------------------
template<int EPI, int BN>
__global__ __launch_bounds__(256) void gemm_glds(
    const unsigned short* __restrict__ A, const unsigned short* __restrict__ Bt,
    const float* __restrict__ bias, void* __restrict__ Cp,
    unsigned short* __restrict__ kfbp, unsigned short* __restrict__ vfbp,
    int M, int N, int K) {
    constexpr int NI = BN / 32;
    __shared__ __align__(16) unsigned short Al[128 * 64];
    __shared__ __align__(16) unsigned short Bl[BN * 64];

    const int tid  = threadIdx.x;
    const int lane = tid & 63;
    const int w    = tid >> 6;
    const int c16  = lane & 15;
    const int quad = lane >> 4;
    const int NT  = N / BN;
    const int pe  = NT >> 3;
    const int xcd = blockIdx.x & 7;
    const int ii  = blockIdx.x >> 3;
    const int n0  = (xcd * pe + ii % pe) * BN;
    const int m0  = (ii / pe) * 128;
    const int wm = (w >> 1) * 64;
    const int wn = (w & 1) * (BN / 2);

    floatx4 acc[4][NI] = {};

    const int srow = lane >> 3;
    const int sch  = ((lane & 7) ^ srow) * 8;
    const unsigned short* ag = A + (size_t)(m0 + w * 32 + srow) * K + sch;
    const unsigned short* bg = Bt + (size_t)(n0 + w * (BN / 4) + srow) * K + sch;

    const int s7 = c16 & 7;

    for (int k0 = 0; k0 < K; k0 += 64) {
        __syncthreads();
#pragma unroll
        for (int i = 0; i < 4; i++)
            glds16(ag + k0 + (size_t)(i * 8) * K, &Al[(w * 32 + i * 8) * 64]);
#pragma unroll
        for (int i = 0; i < BN / 32; i++)
            glds16(bg + k0 + (size_t)(i * 8) * K,
                   &Bl[(w * (BN / 4) + i * 8) * 64]);
        __syncthreads();

        short8 af[4][2], bf[NI][2];
#pragma unroll
        for (int im = 0; im < 4; im++)
#pragma unroll
            for (int kk = 0; kk < 2; kk++)
                af[im][kk] = *reinterpret_cast<const short8*>(
                    &Al[(wm + im * 16 + c16) * 64 + ((kk * 4 + quad) ^ s7) * 8]);
#pragma unroll
        for (int in = 0; in < NI; in++)
#pragma unroll
            for (int kk = 0; kk < 2; kk++)
                bf[in][kk] = *reinterpret_cast<const short8*>(
                    &Bl[(wn + in * 16 + c16) * 64 + ((kk * 4 + quad) ^ s7) * 8]);
#pragma unroll
        for (int im = 0; im < 4; im++)
#pragma unroll
            for (int in = 0; in < NI; in++)
#pragma unroll
                for (int kk = 0; kk < 2; kk++)
                    acc[im][in] = __builtin_amdgcn_mfma_f32_16x16x32_bf16(
                        af[im][kk], bf[in][kk], acc[im][in], 0, 0, 0);
    }

    const int ncol = n0 + wn;
    float bv[NI];
#pragma unroll
    for (int in = 0; in < NI; in++) bv[in] = bias[ncol + in * 16 + c16];

    if (EPI == 0) {
        float* C = (float*)Cp;
#pragma unroll
        for (int im = 0; im < 4; im++)
#pragma unroll
            for (int r = 0; r < 4; r++) {
                int row = m0 + wm + im * 16 + quad * 4 + r;
#pragma unroll
                for (int in = 0; in < NI; in++)
                    C[(size_t)row * N + ncol + in * 16 + c16] =
                        acc[im][in][r] + bv[in];
            }
    } else {
        if (ncol < C_) {                 // Q -> qb[4096][1024], pre-scaled
            unsigned short* qb = (unsigned short*)Cp;
#pragma unroll
            for (int im = 0; im < 4; im++)
#pragma unroll
                for (int r = 0; r < 4; r++) {
                    int row = m0 + wm + im * 16 + quad * 4 + r;
#pragma unroll
                    for (int in = 0; in < NI; in++)
                        qb[(size_t)row * C_ + ncol + in * 16 + c16] =
                            f2b((acc[im][in][r] + bv[in]) * QSCALE);
                }
        } else if (ncol < 2 * C_) {      // K -> kfb fragment-major
            // frag = ws*4+sub*2+dh; lane ll=(quad_d,c16_k); elem j = d&7.
            // 4 consecutive keys (r) -> ll..ll+3: 4x2B stores in one 64B line.
#pragma unroll
            for (int im = 0; im < 4; im++) {
                int row0 = m0 + wm + im * 16 + quad * 4;   // token base (%4==0)
                int b    = row0 >> 11;
                int key  = row0 & (T_ - 1);
                int chunk = key >> 6;
                int kk    = key & 63;
                int wsd   = kk >> 5;
                int subd  = (kk >> 4) & 1;
                int c16d  = kk & 15;
#pragma unroll
                for (int in = 0; in < NI; in++) {
                    int dfull = ncol - C_ + in * 16 + c16;
                    int hh = dfull >> 6;
                    int d  = dfull & 63;
                    size_t base =
                        ((size_t)((b * 16 + hh) * 32 + chunk)) * 4096 +
                        (wsd * 4 + subd * 2 + (d >> 5)) * 512 +
                        (((d >> 3) & 3) * 16 + c16d) * 8 + (d & 7);
#pragma unroll
                    for (int r = 0; r < 4; r++)
                        kfbp[base + (size_t)r * 8] =
                            f2b(acc[im][in][r] + bv[in]);
                }
            }
        } else {                         // V -> vfb fragment-major
            // frag = ws*4+dt; lane ll=(quad_k,c16_d); 4 keys -> contiguous
            // j = jb..jb+3: one 8B short4v store (same count as old vt).
#pragma unroll
            for (int im = 0; im < 4; im++) {
                int row0 = m0 + wm + im * 16 + quad * 4;
                int b    = row0 >> 11;
                int key  = row0 & (T_ - 1);
                int chunk = key >> 6;
                int kk    = key & 63;
                int wsd   = kk >> 5;
                int qd    = (kk >> 2) & 3;
                int jb    = (kk & 16) ? 4 : 0;
#pragma unroll
                for (int in = 0; in < NI; in++) {
                    int dfull = ncol - 2 * C_ + in * 16 + c16;
                    int hh = dfull >> 6;
                    int d  = dfull & 63;
                    short4v sv;
#pragma unroll
                    for (int r = 0; r < 4; r++)
                        sv[r] = (short)f2b(acc[im][in][r] + bv[in]);
                    *reinterpret_cast<short4v*>(
                        &vfbp[((size_t)((b * 16 + hh) * 32 + chunk)) * 4096 +
                              (wsd * 4 + (d >> 4)) * 512 +
                              (qd * 16 + (d & 15)) * 8 + jb]) = sv;
                }
            }
        }
    }
}

// ---------------------------------------------------------------------------
// Load one chunk's 8 fragment-major b128 operands into NAMED registers.
// ---------------------------------------------------------------------------
#define ATTN_LOADF(K0, K1, K2, K3, V0, V1, V2, V3, cc)                        \
{                                                                             \
    const unsigned short* kcp_ = kfp + (size_t)(cc) * 4096;                   \
    const unsigned short* vcp_ = vfp + (size_t)(cc) * 4096;                   \
    K0 = *reinterpret_cast<const short8*>(kcp_);                              \
    K1 = *reinterpret_cast<const short8*>(kcp_ + 512);                        \
    K2 = *reinterpret_cast<const short8*>(kcp_ + 1024);                       \
    K3 = *reinterpret_cast<const short8*>(kcp_ + 1536);                       \
    V0 = *reinterpret_cast<const short8*>(vcp_);                              \
    V1 = *reinterpret_cast<const short8*>(vcp_ + 512);                        \
    V2 = *reinterpret_cast<const short8*>(vcp_ + 1024);                       \
    V3 = *reinterpret_cast<const short8*>(vcp_ + 1536);                       \
}

// ---------------------------------------------------------------------------
// Compute one 64-key chunk from named frags (round-8/10/11-verified math):
// S^T per 16-key sub; softmax exp2 (+causal mask if MASKED); PV window
// {sub0:quad*4+r, sub1:+16}; l via ones-MFMA. All O/O1 indices literal.
// ---------------------------------------------------------------------------
#define ATTN_COMPUTE(MASKED, kb, K0, K1, K2, K3, V0, V1, V2, V3)              \
{                                                                             \
    short8 pf0, pf1;                                                          \
    _Pragma("unroll")                                                         \
    for (int qt = 0; qt < 2; qt++) {                                          \
        floatx4 s0 = __builtin_amdgcn_mfma_f32_16x16x32_bf16(                 \
            K0, af[qt][0], z, 0, 0, 0);                                       \
        s0 = __builtin_amdgcn_mfma_f32_16x16x32_bf16(                         \
            K1, af[qt][1], s0, 0, 0, 0);                                      \
        floatx4 s1 = __builtin_amdgcn_mfma_f32_16x16x32_bf16(                 \
            K2, af[qt][0], z, 0, 0, 0);                                       \
        s1 = __builtin_amdgcn_mfma_f32_16x16x32_bf16(                         \
            K3, af[qt][1], s1, 0, 0, 0);                                      \
        short8 p8;                                                            \
        _Pragma("unroll")                                                     \
        for (int r = 0; r < 4; r++) {                                         \
            float p0, p1;                                                     \
            if (MASKED) {                                                     \
                int key0 = (kb) + ws * 32 + quad * 4 + r;                     \
                int qr = q0 + wq * 32 + qt * 16 + c16;                        \
                p0 = (key0 <= qr) ? fexp2(s0[r]) : 0.f;                       \
                p1 = (key0 + 16 <= qr) ? fexp2(s1[r]) : 0.f;                  \
            } else {                                                          \
                p0 = fexp2(s0[r]);                                            \
                p1 = fexp2(s1[r]);                                            \
            }                                                                 \
            p8[r] = (short)f2b(p0);                                           \
            p8[4 + r] = (short)f2b(p1);                                       \
        }                                                                     \
        if (qt == 0) pf0 = p8; else pf1 = p8;                                 \
    }                                                                         \
    O1[0] = __builtin_amdgcn_mfma_f32_16x16x32_bf16(pf0, ones, O1[0], 0, 0, 0); \
    O1[1] = __builtin_amdgcn_mfma_f32_16x16x32_bf16(pf1, ones, O1[1], 0, 0, 0); \
    O[0][0] = __builtin_amdgcn_mfma_f32_16x16x32_bf16(pf0, V0, O[0][0], 0, 0, 0); \
    O[1][0] = __builtin_amdgcn_mfma_f32_16x16x32_bf16(pf1, V0, O[1][0], 0, 0, 0); \
    O[0][1] = __builtin_amdgcn_mfma_f32_16x16x32_bf16(pf0, V1, O[0][1], 0, 0, 0); \
    O[1][1] = __builtin_amdgcn_mfma_f32_16x16x32_bf16(pf1, V1, O[1][1], 0, 0, 0); \
    O[0][2] = __builtin_amdgcn_mfma_f32_16x16x32_bf16(pf0, V2, O[0][2], 0, 0, 0); \
    O[1][2] = __builtin_amdgcn_mfma_f32_16x16x32_bf16(pf1, V2, O[1][2], 0, 0, 0); \
    O[0][3] = __builtin_amdgcn_mfma_f32_16x16x32_bf16(pf0, V3, O[0][3], 0, 0, 0); \
    O[1][3] = __builtin_amdgcn_mfma_f32_16x16x32_bf16(pf1, V3, O[1][3], 0, 0, 0); \
}

// ---------------------------------------------------------------------------
// Flash attention, 2x2 wave split, zero-LDS main loop, fragment-major K/V,
// 2-deep register prefetch (named sets A/B, 2-unrolled loop). Block = 256
// thr = 4 waves; block t owns Q rows [64t,64t+64), nch=t+1, LPT. Wave w:
// q-half wq=w&1 (Q in regs from qb), key-half ws=w>>1. No barriers in the
// loop. Pair merge through 20KB LDS (one barrier). All O/O1 indices
// compile-time (rule #20). Fully-masked {wq0,ws1} diagonal corner skipped.
// launch_bounds(256,2): VGPR cap 256 — prefetch set (+64 regs, ~150 total)
// cannot spill. DO NOT tighten (round-9: cap 84 -> 314MB spill).
// ---------------------------------------------------------------------------
__global__ __launch_bounds__(256, 2) void attn_mfma(
    const unsigned short* __restrict__ qk,
    const unsigned short* __restrict__ kfb,
    const unsigned short* __restrict__ vfb,
    unsigned short* __restrict__ y) {
    __shared__ __align__(16) float Of[4096];   // [wq][qt][dt][lane][4]
    __shared__ __align__(16) float Lb[1024];   // [wq][qt][lane][4] (O1 park)

    const int tid  = threadIdx.x;
    const int lane = tid & 63;
    const int w    = tid >> 6;          // 0..3
    const int wq   = w & 1;             // q-half
    const int ws   = w >> 1;            // key-half
    const int c16  = lane & 15;
    const int quad = lane >> 4;
    const int bh = blockIdx.x & 31;
    const int t  = 31 - (blockIdx.x >> 5);   // longest-first
    const int b  = bh >> 4;
    const int h  = bh & 15;
    const int q0 = t * 64;
    const int nch = t + 1;

    const unsigned short* qrow = qk + (size_t)b * T_ * C_ + h * HD_;
    const unsigned short* kfp = kfb + ((size_t)bh * 32) * 4096 + ws * 2048 + lane * 8;
    const unsigned short* vfp = vfb + ((size_t)bh * 32) * 4096 + ws * 2048 + lane * 8;

    // Q in registers: af[qt][hh] = Q[q0+wq*32+qt*16+c16][hh*32+quad*8 ..+8]
    short8 af[2][2];
#pragma unroll
    for (int qt = 0; qt < 2; qt++)
#pragma unroll
        for (int hh = 0; hh < 2; hh++)
            af[qt][hh] = *reinterpret_cast<const short8*>(
                qrow + (size_t)(q0 + wq * 32 + qt * 16 + c16) * C_ +
                hh * 32 + quad * 8);

    floatx4 O[2][4] = {};
    floatx4 O1[2] = {};                  // row-sums l via ones-MFMA
    const floatx4 z = {0.f, 0.f, 0.f, 0.f};
    short8 ones;
#pragma unroll
    for (int j = 0; j < 8; j++) ones[j] = (short)0x3F80;   // bf16 1.0

    // 2-deep prefetch pipeline: named sets A/B, alternating.
    short8 A0, A1, A2, A3, AV0, AV1, AV2, AV3;
    short8 B0, B1, B2, B3, BV0, BV1, BV2, BV3;
    ATTN_LOADF(A0, A1, A2, A3, AV0, AV1, AV2, AV3, 0);
    int c = 0;
    for (;;) {
        if (c + 1 < nch) {
            ATTN_LOADF(B0, B1, B2, B3, BV0, BV1, BV2, BV3, c + 1);
            ATTN_COMPUTE(0, c * 64, A0, A1, A2, A3, AV0, AV1, AV2, AV3);
        } else {
            if (!(wq == 0 && ws == 1))   // diagonal; fully-masked corner skip
                ATTN_COMPUTE(1, c * 64, A0, A1, A2, A3, AV0, AV1, AV2, AV3);
            break;
        }
        c++;
        if (c + 1 < nch) {
            ATTN_LOADF(A0, A1, A2, A3, AV0, AV1, AV2, AV3, c + 1);
            ATTN_COMPUTE(0, c * 64, B0, B1, B2, B3, BV0, BV1, BV2, BV3);
        } else {
            if (!(wq == 0 && ws == 1))
                ATTN_COMPUTE(1, c * 64, B0, B1, B2, B3, BV0, BV1, BV2, BV3);
            break;
        }
        c++;
    }

    // ---- pair merge: O_total = O(ws=0) + O(ws=1) per q-half.
    // ws=1 parks O (32 f32/lane) + O1 in LDS; ws=0 partners add and write.
    if (ws) {
#pragma unroll
        for (int qt = 0; qt < 2; qt++) {
#pragma unroll
            for (int dt = 0; dt < 4; dt++)
                *reinterpret_cast<floatx4*>(
                    &Of[wq * 2048 + qt * 1024 + dt * 256 + lane * 4]) = O[qt][dt];
            *reinterpret_cast<floatx4*>(
                &Lb[wq * 512 + qt * 256 + lane * 4]) = O1[qt];
        }
    }
    __syncthreads();
    if (ws == 0) {
#pragma unroll
        for (int qt = 0; qt < 2; qt++) {
#pragma unroll
            for (int dt = 0; dt < 4; dt++)
                O[qt][dt] += *reinterpret_cast<const floatx4*>(
                    &Of[wq * 2048 + qt * 1024 + dt * 256 + lane * 4]);
            floatx4 lr = O1[qt] + *reinterpret_cast<const floatx4*>(
                    &Lb[wq * 512 + qt * 256 + lane * 4]);

            // write rows q0+wq*32+qt*16+quad*4+r, cols h*HD+dt*16+c16
#pragma unroll
            for (int dt = 0; dt < 4; dt++)
#pragma unroll
                for (int r = 0; r < 4; r++) {
                    float val = O[qt][dt][r] / fmaxf(lr[r], 1e-30f);
                    y[((size_t)b * T_ + q0 + wq * 32 + qt * 16 + quad * 4 + r)
                          * C_ + h * HD_ + dt * 16 + c16] = f2b(val);
                }
        }
    }
}

extern "C" void kernel_launch(void* const* d_in, const int* in_sizes, int n_in,
                              void* d_out, int out_size, void* d_ws, size_t ws_size,
                              hipStream_t stream) {
    const float* x     = (const float*)d_in[0];
    const float* w_qkv = (const float*)d_in[1];
    const float* b_qkv = (const float*)d_in[2];
    const float* w_out = (const float*)d_in[3];
    const float* b_out = (const float*)d_in[4];
    float* out = (float*)d_out;

    unsigned short* qb  = (unsigned short*)d_ws;                 // [4096][1024]
    unsigned short* kfb = qb + (size_t)M_ * C_;                  // [32*32][4096]
    unsigned short* vfb = kfb + (size_t)32 * 32 * 4096;          // [32*32][4096]
    unsigned short* yb  = vfb + (size_t)32 * 32 * 4096;          // [4096][1024]
    unsigned short* wt1 = yb + (size_t)M_ * C_;                  // [3072][1024]
    unsigned short* wt2 = wt1 + (size_t)N3_ * C_;                // [1024][1024]
    unsigned short* xb  = wt2 + (size_t)C_ * C_;                 // [4096][1024]

    prep<<<2048 + 1536 + 512, 256, 0, stream>>>(x, w_qkv, w_out, xb, wt1, wt2);

    gemm_glds<1, 128><<<(N3_ / 128) * (M_ / 128), 256, 0, stream>>>(
        xb, wt1, b_qkv, qb, kfb, vfb, M_, N3_, C_);

    attn_mfma<<<B_ * H_ * 32, 256, 0, stream>>>(qb, kfb, vfb, yb);

    gemm_glds<0, 64><<<(C_ / 64) * (M_ / 128), 256, 0, stream>>>(
        yb, wt2, b_out, out, nullptr, nullptr, M_, C_, C_);
}